// Round 15
// baseline (160.505 us; speedup 1.0000x reference)
//
#include <hip/hip_runtime.h>
#include <math.h>

// Fused HENN MLP: gather -> segment_sum -> Linear(256,256)+ReLU -> Linear(256,1) -> sigmoid
//
// R15 = R13/R14 (GEMM-before-gather restructure) with gemm_h rebuilt LDS-free:
//   R14 counters: gemm 63us, MfmaUtil 7%, VALU 11%, occ 23% -> latency-bound;
//   the 32KB LDS tile (5 blocks/CU cap) + stage->barrier->MFMA serial chain
//   starved the CU. New gemm: no LDS, no barrier. Block = 64 nodes; its 4
//   waves split h (64 each) and read the SAME x rows straight from L1/L2
//   (4x re-read ~306MB L2 @34TB/s ~ 9us, cheaper than lost occupancy).
//   B-frags: two f4 loads of f32 x + v_perm hi16 truncation -> bf16x8.
//   A-frags: W1b rows from L2 (R14-verified). Store: R14's packed u2.
//
// Pipeline (3 launches):
//  1. prep2:      W1 f32->bf16 + seg_ptr build (tiny)
//  2. gemm_h:     H = x @ W1^T (bf16), LDS-free as above
//  3. gather_out: R7 gather engine + fused layer-2 epilogue (verified, 62us,
//                 logical delivery ~6.6 TB/s = streaming ceiling)
//
// Falls back to the R4-style fused f32 kernel if ws_size is too small.

typedef __attribute__((ext_vector_type(8))) short bf16x8;
typedef __attribute__((ext_vector_type(4))) float f32x4;
typedef __attribute__((ext_vector_type(4))) float f4;
typedef __attribute__((ext_vector_type(4))) unsigned u4;
typedef __attribute__((ext_vector_type(2))) unsigned u2;

__device__ __forceinline__ ushort f2bf(float f) {   // RNE f32->bf16
  unsigned u = __float_as_uint(f);
  return (ushort)((u + 0x7FFF + ((u >> 16) & 1)) >> 16);
}
__device__ __forceinline__ unsigned pack2(float lo, float hi) {
  return (unsigned)f2bf(lo) | ((unsigned)f2bf(hi) << 16);
}
// hi16 of two f32 packed into one u32 (bf16 truncation): low half from lo
__device__ __forceinline__ unsigned hi2(float lo, float hi) {
  return __builtin_amdgcn_perm(__float_as_uint(hi), __float_as_uint(lo),
                               0x07060302u);
}

#define PREP_W1_BLOCKS 64

__global__ __launch_bounds__(256) void prep2(
    const float* __restrict__ W1, ushort* __restrict__ W1b,
    const int* __restrict__ tids, int* __restrict__ ptr, int P, int E)
{
  const int b = blockIdx.x;
  if (b < PREP_W1_BLOCKS) {
    const int base = (b * 256 + threadIdx.x) * 4;
    if (base < 256 * 256) {
      const f4 v = *(const f4*)(W1 + base);
      u2 o; o.x = pack2(v.x, v.y); o.y = pack2(v.z, v.w);
      *(u2*)(W1b + base) = o;
    }
  } else {
    const int p = (b - PREP_W1_BLOCKS) * 256 + threadIdx.x;
    if (p >= P) return;
    const int v = tids[p];
    const int prev = (p == 0) ? -1 : tids[p - 1];
    for (int e = prev + 1; e <= v; ++e) ptr[e] = p;
    if (p == P - 1) {
      for (int e = v + 1; e <= E; ++e) ptr[e] = P;
    }
  }
}

// H = x @ W1^T (bf16 out). LDS-free: block = 64 nodes, 4 waves split h.
__global__ __launch_bounds__(256) void gemm_h(
    const float* __restrict__ x,
    const ushort* __restrict__ W1b,
    ushort* __restrict__ Hb,
    int N)
{
  const int tid  = threadIdx.x;
  const int wid  = tid >> 6;            // 0..3 -> h-slice [64*wid, +64)
  const int lane = tid & 63;
  const int l15  = lane & 15;
  const int l4   = lane >> 4;
  const int nb   = blockIdx.x * 64;     // block's 64 nodes
  const int h0   = wid * 64;

  // per-nt x row base (clamped tail; duplicate reads harmless, stores guarded)
  const float* xrow[4];
#pragma unroll
  for (int nt = 0; nt < 4; ++nt)
    xrow[nt] = x + (size_t)min(nb + nt * 16 + l15, N - 1) * 256;

  f32x4 acc[4][4];
#pragma unroll
  for (int mt = 0; mt < 4; ++mt)
#pragma unroll
    for (int nt = 0; nt < 4; ++nt)
      acc[mt][nt] = (f32x4){0.f, 0.f, 0.f, 0.f};

#pragma unroll 2
  for (int kk = 0; kk < 8; ++kk) {
    bf16x8 a[4];    // W1 fragments (A: M = h), L2-resident
#pragma unroll
    for (int mt = 0; mt < 4; ++mt) {
      const int h = h0 + mt * 16 + l15;
      a[mt] = *(const bf16x8*)(W1b + (size_t)h * 256 + kk * 32 + l4 * 8);
    }
#pragma unroll
    for (int nt = 0; nt < 4; ++nt) {
      // B fragment: x[node][kk*32 + l4*8 .. +8] as bf16 (hi16 truncation)
      const float* bp = xrow[nt] + kk * 32 + l4 * 8;
      const f4 v0 = *(const f4*)bp;
      const f4 v1 = *(const f4*)(bp + 4);
      u4 pk;
      pk.x = hi2(v0.x, v0.y); pk.y = hi2(v0.z, v0.w);
      pk.z = hi2(v1.x, v1.y); pk.w = hi2(v1.z, v1.w);
      const bf16x8 b = __builtin_bit_cast(bf16x8, pk);
#pragma unroll
      for (int mt = 0; mt < 4; ++mt)
        acc[mt][nt] = __builtin_amdgcn_mfma_f32_16x16x32_bf16(a[mt], b, acc[mt][nt], 0, 0, 0);
    }
  }

  // store: Hb[node][h..h+3] as one u2 (8B) per acc tile (R14-verified mapping:
  // row(M)=h = h0+mt*16+l4*4+r, col(N)=node = nb+nt*16+l15)
  const bool full = (nb + 64 <= N);
#pragma unroll
  for (int nt = 0; nt < 4; ++nt) {
    const int node = nb + nt * 16 + l15;
    if (full || node < N) {
      ushort* rowp = Hb + (size_t)node * 256;
#pragma unroll
      for (int mt = 0; mt < 4; ++mt) {
        const int h = h0 + mt * 16 + l4 * 4;
        u2 o;
        o.x = pack2(acc[mt][nt][0], acc[mt][nt][1]);
        o.y = pack2(acc[mt][nt][2], acc[mt][nt][3]);
        *(u2*)(rowp + h) = o;
      }
    }
  }
}

// R7 gather engine + fused layer-2 epilogue. out[e] = sigmoid(W2.relu(sum+b1)+b2)
__global__ __launch_bounds__(128, 8) void gather_out(
    const ushort* __restrict__ Hb,
    const int* __restrict__ tnodes,
    const int* __restrict__ ptr,
    const float* __restrict__ b1,
    const float* __restrict__ W2,
    const float* __restrict__ b2,
    float* __restrict__ out,
    int E)
{
  const int lane = threadIdx.x & 63;
  const int wid  = threadIdx.x >> 6;             // 0..1
  const int e0   = blockIdx.x * 16 + wid * 8;    // this wave's 8 segments
  if (e0 >= E) return;
  const int nseg = min(8, E - e0);

  int bnd = 0;
  if (lane <= 8) bnd = ptr[min(e0 + lane, E)];   // bounds for segs e0..e0+8
  const int plo = __builtin_amdgcn_readfirstlane(__shfl(bnd, 0));
  const int phi = __builtin_amdgcn_readfirstlane(__shfl(bnd, nseg));
  const int total = phi - plo;                   // SGPR

  // per-lane epilogue coefficients: this lane owns cols lane*4 .. lane*4+3
  const int c0 = lane * 4;
  const float b1v0 = b1[c0], b1v1 = b1[c0 + 1], b1v2 = b1[c0 + 2], b1v3 = b1[c0 + 3];
  const float w2v0 = W2[c0], w2v1 = W2[c0 + 1], w2v2 = W2[c0 + 2], w2v3 = W2[c0 + 3];
  const float b2v = b2[0];

  const char* xbB = (const char*)Hb;
  const int lb = lane * 8;                       // byte offset within 512B row

  float a0 = 0.f, a1 = 0.f, a2 = 0.f, a3 = 0.f;
  int s = 0;
  int hi_s = __builtin_amdgcn_readfirstlane(__shfl(bnd, 1));

#define FLUSHOUT()                                                            \
  {                                                                           \
    float p = w2v0 * fmaxf(a0 + b1v0, 0.f);                                   \
    p = fmaf(w2v1, fmaxf(a1 + b1v1, 0.f), p);                                 \
    p = fmaf(w2v2, fmaxf(a2 + b1v2, 0.f), p);                                 \
    p = fmaf(w2v3, fmaxf(a3 + b1v3, 0.f), p);                                 \
    p += __shfl_xor(p, 1);  p += __shfl_xor(p, 2);                            \
    p += __shfl_xor(p, 4);  p += __shfl_xor(p, 8);                            \
    p += __shfl_xor(p, 16); p += __shfl_xor(p, 32);                           \
    if (lane == 0) out[e0 + s] = 1.f / (1.f + expf(-(p + b2v)));              \
    a0 = a1 = a2 = a3 = 0.f;                                                  \
  }
#define FLUSHCHK(PCUR)                                                        \
  while ((PCUR) >= hi_s) {            /* wave-uniform segment flush */        \
    FLUSHOUT()                                                                \
    ++s; hi_s = __builtin_amdgcn_readfirstlane(__shfl(bnd, min(s + 1, 8)));   \
  }
#define ACCV(V)                                                               \
  a0 += __uint_as_float((V).x << 16);                                         \
  a1 += __uint_as_float((V).x & 0xffff0000u);                                 \
  a2 += __uint_as_float((V).y << 16);                                         \
  a3 += __uint_as_float((V).y & 0xffff0000u);

  if (total > 0) {
    const int tmax = total - 1;
    u2 va[8], vb[8];
    // prologue: fill both banks; indices wave-uniform -> tnodes via s_load
#pragma unroll
    for (int k = 0; k < 8; ++k) {
      const int p = plo + min(k, tmax);
      va[k] = *(const u2*)(xbB + (size_t)tnodes[p] * 512 + lb);
    }
#pragma unroll
    for (int k = 0; k < 8; ++k) {
      const int p = plo + min(8 + k, tmax);
      vb[k] = *(const u2*)(xbB + (size_t)tnodes[p] * 512 + lb);
    }

    for (int j = 0; j < total; j += 16) {
      // consume bank A (pairs j..j+8)
#pragma unroll
      for (int k = 0; k < 8; ++k) {
        const int pc = j + k;
        if (pc < total) { FLUSHCHK(plo + pc) ACCV(va[k]) }
      }
      // refill bank A for pairs [j+16, j+24)
#pragma unroll
      for (int k = 0; k < 8; ++k) {
        const int p = plo + min(j + 16 + k, tmax);
        va[k] = *(const u2*)(xbB + (size_t)tnodes[p] * 512 + lb);
      }
      // consume bank B (pairs j+8..j+16)
#pragma unroll
      for (int k = 0; k < 8; ++k) {
        const int pc = j + 8 + k;
        if (pc < total) { FLUSHCHK(plo + pc) ACCV(vb[k]) }
      }
      // refill bank B for pairs [j+24, j+32)
#pragma unroll
      for (int k = 0; k < 8; ++k) {
        const int p = plo + min(j + 24 + k, tmax);
        vb[k] = *(const u2*)(xbB + (size_t)tnodes[p] * 512 + lb);
      }
    }
  }
  // flush remaining segments (incl. trailing empties)
  while (s < nseg) { FLUSHOUT() ++s; }
#undef FLUSHCHK
#undef FLUSHOUT
#undef ACCV
}

// ---------------- R4 fused fallback (ws too small for split path) ----------
__global__ __launch_bounds__(256, 4) void henn_main(
    const float* __restrict__ x,
    const int* __restrict__ tnodes,
    const int* __restrict__ ptr,
    const ushort* __restrict__ W1b,
    const float* __restrict__ b1,
    const float* __restrict__ W2,
    const float* __restrict__ b2,
    float* __restrict__ out,
    int E)
{
  __shared__ __align__(16) ushort Zb[64 * 256];
  const int tid  = threadIdx.x;
  const int wid  = tid >> 6;
  const int lane = tid & 63;
  const int l15  = lane & 15;
  const int l4   = lane >> 4;
  const int e0   = blockIdx.x * 64;

  int bidx = e0 + wid * 16 + lane;
  int bnd = 0;
  if (lane < 17) bnd = ptr[min(bidx, E)];

  for (int s = 0; s < 16; ++s) {
    const int lo = __shfl(bnd, s);
    const int hi = __shfl(bnd, s + 1);
    float4 a0 = {0,0,0,0}, a1 = {0,0,0,0}, a2 = {0,0,0,0}, a3 = {0,0,0,0};
    for (int base = lo; base < hi; base += 64) {
      const int cnt = min(64, hi - base);
      const int nd = (lane < cnt) ? tnodes[base + lane] : 0;
      const int rounds = (cnt + 3) >> 2;
      for (int r = 0; r < rounds; ++r) {
        const int idx = r * 4 + l4;
        const int node = __shfl(nd, min(idx, cnt - 1));
        if (idx < cnt) {
          const float4* rowp = (const float4*)(x + (size_t)node * 256) + l15;
          const float4 v0 = rowp[0];
          const float4 v1 = rowp[16];
          const float4 v2 = rowp[32];
          const float4 v3 = rowp[48];
          a0.x += v0.x; a0.y += v0.y; a0.z += v0.z; a0.w += v0.w;
          a1.x += v1.x; a1.y += v1.y; a1.z += v1.z; a1.w += v1.w;
          a2.x += v2.x; a2.y += v2.y; a2.z += v2.z; a2.w += v2.w;
          a3.x += v3.x; a3.y += v3.y; a3.z += v3.z; a3.w += v3.w;
        }
      }
    }
    a0.x += __shfl_xor(a0.x,16); a0.y += __shfl_xor(a0.y,16); a0.z += __shfl_xor(a0.z,16); a0.w += __shfl_xor(a0.w,16);
    a0.x += __shfl_xor(a0.x,32); a0.y += __shfl_xor(a0.y,32); a0.z += __shfl_xor(a0.z,32); a0.w += __shfl_xor(a0.w,32);
    a1.x += __shfl_xor(a1.x,16); a1.y += __shfl_xor(a1.y,16); a1.z += __shfl_xor(a1.z,16); a1.w += __shfl_xor(a1.w,16);
    a1.x += __shfl_xor(a1.x,32); a1.y += __shfl_xor(a1.y,32); a1.z += __shfl_xor(a1.z,32); a1.w += __shfl_xor(a1.w,32);
    a2.x += __shfl_xor(a2.x,16); a2.y += __shfl_xor(a2.y,16); a2.z += __shfl_xor(a2.z,16); a2.w += __shfl_xor(a2.w,16);
    a2.x += __shfl_xor(a2.x,32); a2.y += __shfl_xor(a2.y,32); a2.z += __shfl_xor(a2.z,32); a2.w += __shfl_xor(a2.w,32);
    a3.x += __shfl_xor(a3.x,16); a3.y += __shfl_xor(a3.y,16); a3.z += __shfl_xor(a3.z,16); a3.w += __shfl_xor(a3.w,16);
    a3.x += __shfl_xor(a3.x,32); a3.y += __shfl_xor(a3.y,32); a3.z += __shfl_xor(a3.z,32); a3.w += __shfl_xor(a3.w,32);
    float4 m = (l4 == 0) ? a0 : (l4 == 1) ? a1 : (l4 == 2) ? a2 : a3;
    const int row = wid * 16 + s;
    ushort4 o; o.x = f2bf(m.x); o.y = f2bf(m.y); o.z = f2bf(m.z); o.w = f2bf(m.w);
    const int waddr = row * 512 + lane * 8;
    *(ushort4*)((char*)Zb + (waddr ^ ((row & 7) << 4))) = o;
  }
  __syncthreads();

  const int n0 = wid * 64;
  f32x4 acc[4][4];
#pragma unroll
  for (int mt = 0; mt < 4; ++mt)
#pragma unroll
    for (int nt = 0; nt < 4; ++nt)
      acc[mt][nt] = (f32x4){0.f, 0.f, 0.f, 0.f};
#pragma unroll
  for (int kk = 0; kk < 8; ++kk) {
    bf16x8 a[4];
#pragma unroll
    for (int mt = 0; mt < 4; ++mt) {
      const int row = mt * 16 + l15;
      const int raddr = row * 512 + kk * 64 + l4 * 16;
      a[mt] = *(const bf16x8*)((const char*)Zb + (raddr ^ ((row & 7) << 4)));
    }
#pragma unroll
    for (int nt = 0; nt < 4; ++nt) {
      const int h = n0 + nt * 16 + l15;
      const bf16x8 b = *(const bf16x8*)(W1b + (size_t)h * 256 + kk * 32 + l4 * 8);
#pragma unroll
      for (int mt = 0; mt < 4; ++mt)
        acc[mt][nt] = __builtin_amdgcn_mfma_f32_16x16x32_bf16(a[mt], b, acc[mt][nt], 0, 0, 0);
    }
  }
  __syncthreads();

  float b1h[4], w2v[4];
#pragma unroll
  for (int nt = 0; nt < 4; ++nt) {
    const int h = n0 + nt * 16 + l15;
    b1h[nt] = b1[h];
    w2v[nt] = W2[h];
  }
  float* red = (float*)Zb;
#pragma unroll
  for (int mt = 0; mt < 4; ++mt) {
#pragma unroll
    for (int r = 0; r < 4; ++r) {
      float p = 0.f;
#pragma unroll
      for (int nt = 0; nt < 4; ++nt) {
        const float y = acc[mt][nt][r] + b1h[nt];
        p = fmaf(w2v[nt], fmaxf(y, 0.f), p);
      }
      p += __shfl_xor(p, 1);
      p += __shfl_xor(p, 2);
      p += __shfl_xor(p, 4);
      p += __shfl_xor(p, 8);
      if (l15 == 0) red[wid * 64 + mt * 16 + l4 * 4 + r] = p;
    }
  }
  __syncthreads();

  if (tid < 64) {
    const int e = e0 + tid;
    if (e < E) {
      const float v = red[tid] + red[64 + tid] + red[128 + tid] + red[192 + tid] + b2[0];
      out[e] = 1.f / (1.f + expf(-v));
    }
  }
}

extern "C" void kernel_launch(void* const* d_in, const int* in_sizes, int n_in,
                              void* d_out, int out_size, void* d_ws, size_t ws_size,
                              hipStream_t stream) {
  const float* x      = (const float*)d_in[0];
  const int*   tnodes = (const int*)d_in[1];
  const int*   tids   = (const int*)d_in[2];
  const float* W1     = (const float*)d_in[3];
  const float* b1     = (const float*)d_in[4];
  const float* W2     = (const float*)d_in[5];
  const float* b2     = (const float*)d_in[6];
  (void)n_in;

  const int P       = in_sizes[1];        // 800000
  const int E       = out_size;           // 100000
  const int n_nodes = in_sizes[0] / 256;  // 100000

  const size_t OFF_W1B  = 512 * 1024;
  const size_t OFF_HB   = 1024 * 1024;
  const size_t hb_bytes = (size_t)n_nodes * 512 + 65536;
  const size_t need     = OFF_HB + hb_bytes;

  int*    seg_ptr = (int*)d_ws;
  ushort* W1b     = (ushort*)((char*)d_ws + OFF_W1B);
  ushort* Hb      = (ushort*)((char*)d_ws + OFF_HB);

  const int prep_grid = PREP_W1_BLOCKS + (P + 255) / 256;
  prep2<<<prep_grid, 256, 0, stream>>>(W1, W1b, tids, seg_ptr, P, E);

  if (ws_size >= need) {
    const int gemm_blocks = (n_nodes + 63) / 64;
    gemm_h<<<gemm_blocks, 256, 0, stream>>>(x, W1b, Hb, n_nodes);
    const int gblocks = (E + 15) / 16;
    gather_out<<<gblocks, 128, 0, stream>>>(Hb, tnodes, seg_ptr, b1, W2, b2,
                                            (float*)d_out, E);
  } else {
    const int blocks = (E + 63) / 64;
    henn_main<<<blocks, 256, 0, stream>>>(x, tnodes, seg_ptr, W1b, b1, W2, b2,
                                          (float*)d_out, E);
  }
}

// Round 16
// 102.071 us; speedup vs baseline: 1.5725x; 1.5725x over previous
//
#include <hip/hip_runtime.h>
#include <math.h>

// Fused HENN MLP: gather -> segment_sum -> Linear(256,256)+ReLU -> Linear(256,1) -> sigmoid
//
// R16 = R13 algebraic order (GEMM before gather) with gemm_h rebuilt as a
// PERSISTENT ASYNC kernel:
//  - W1 A-fragments cached in registers once per block (a[4][8], 128 VGPR):
//    W1 leaves the inner loop entirely (R14/R15 re-read 200-400MB from L2).
//  - x tiles staged f32 via global_load_lds (width=16) into a double-buffered
//    LDS with row stride 1040B (260 dwords = 4 mod 32 -> 2-way bank = free).
//    Issue next tile BEFORE computing current; one __syncthreads per tile
//    drains vmcnt (m97 structure).
//  - B-frags: 2x ds_read_b128 f32 + v_perm hi16 truncation (R15-verified).
//  - 512 blocks (2/CU, launch_bounds(256,2) -> 256 VGPR cap, ~195 used),
//    32-node tiles, 3125 tiles total (exact), stores = R14-verified u2 pack.
//
// Pipeline: prep2 (W1->bf16 + segptr) ; gemm_h ; gather_out (verified 62us,
// ~6.6 TB/s logical = ceiling). Fallback: R4 fused kernel if ws too small.

typedef __attribute__((ext_vector_type(8))) short bf16x8;
typedef __attribute__((ext_vector_type(4))) float f32x4;
typedef __attribute__((ext_vector_type(4))) float f4;
typedef __attribute__((ext_vector_type(4))) unsigned u4;
typedef __attribute__((ext_vector_type(2))) unsigned u2;

__device__ __forceinline__ ushort f2bf(float f) {   // RNE f32->bf16
  unsigned u = __float_as_uint(f);
  return (ushort)((u + 0x7FFF + ((u >> 16) & 1)) >> 16);
}
__device__ __forceinline__ unsigned pack2(float lo, float hi) {
  return (unsigned)f2bf(lo) | ((unsigned)f2bf(hi) << 16);
}
// hi16 of two f32 packed into one u32 (bf16 truncation): lo in low half
__device__ __forceinline__ unsigned hi2(float lo, float hi) {
  return __builtin_amdgcn_perm(__float_as_uint(hi), __float_as_uint(lo),
                               0x07060302u);
}

#define PREP_W1_BLOCKS 64
#define GEMM_BLOCKS    512
#define ROWSTRIDE      1040   // f32 row stride in LDS: 16B-aligned, 4 mod 32 dwords

__global__ __launch_bounds__(256) void prep2(
    const float* __restrict__ W1, ushort* __restrict__ W1b,
    const int* __restrict__ tids, int* __restrict__ ptr, int P, int E)
{
  const int b = blockIdx.x;
  if (b < PREP_W1_BLOCKS) {
    const int base = (b * 256 + threadIdx.x) * 4;
    if (base < 256 * 256) {
      const f4 v = *(const f4*)(W1 + base);
      u2 o; o.x = pack2(v.x, v.y); o.y = pack2(v.z, v.w);
      *(u2*)(W1b + base) = o;
    }
  } else {
    const int p = (b - PREP_W1_BLOCKS) * 256 + threadIdx.x;
    if (p >= P) return;
    const int v = tids[p];
    const int prev = (p == 0) ? -1 : tids[p - 1];
    for (int e = prev + 1; e <= v; ++e) ptr[e] = p;
    if (p == P - 1) {
      for (int e = v + 1; e <= E; ++e) ptr[e] = P;
    }
  }
}

// H = x @ W1^T (bf16 out). Persistent, async-staged, W1-in-registers.
__global__ __launch_bounds__(256, 2) void gemm_h(
    const float* __restrict__ x,
    const ushort* __restrict__ W1b,
    ushort* __restrict__ Hb,
    int N, int T)
{
  __shared__ __align__(16) char lds[2 * 32 * ROWSTRIDE];   // 2 x 33280 B
  const int tid  = threadIdx.x;
  const int wid  = tid >> 6;            // 0..3 -> h-slice [64*wid, +64)
  const int lane = tid & 63;
  const int l15  = lane & 15;
  const int l4   = lane >> 4;
  const int h0   = wid * 64;

  // ---- cache W1 A-fragments once: a[mt][kk] (128 VGPR, loop-invariant) ----
  bf16x8 a[4][8];
#pragma unroll
  for (int mt = 0; mt < 4; ++mt) {
    const int h = h0 + mt * 16 + l15;
#pragma unroll
    for (int kk = 0; kk < 8; ++kk)
      a[mt][kk] = *(const bf16x8*)(W1b + (size_t)h * 256 + kk * 32 + l4 * 8);
  }

  int t = blockIdx.x;
  if (t >= T) return;

  // stage tile T_ into buffer BUF_ (8 async 16B/lane loads; wave = 1 row/chunk)
#define STAGE(T_, BUF_)                                                       \
  {                                                                           \
    const int tb_ = (T_) * 32;                                                \
    _Pragma("unroll")                                                         \
    for (int i = 0; i < 8; ++i) {                                             \
      const int row_ = i * 4 + wid;                                           \
      const int node_ = min(tb_ + row_, N - 1);                               \
      const float* g_ = x + (size_t)node_ * 256 + lane * 4;                   \
      char* l_ = (BUF_) + row_ * ROWSTRIDE;                                   \
      __builtin_amdgcn_global_load_lds(                                       \
          (const __attribute__((address_space(1))) unsigned*)g_,              \
          (__attribute__((address_space(3))) unsigned*)l_, 16, 0, 0);         \
    }                                                                         \
  }

  STAGE(t, lds)            // prologue -> buffer 0
  __syncthreads();         // drains vmcnt: buffer 0 ready

  int cur = 0;
  for (; t < T; t += GEMM_BLOCKS) {
    const int tn = t + GEMM_BLOCKS;
    char* nbuf = lds + (cur ^ 1) * (32 * ROWSTRIDE);
    if (tn < T) STAGE(tn, nbuf)          // issue early; lands by next barrier

    // ---- compute tile t from buf[cur] ----
    const char* zb = lds + cur * (32 * ROWSTRIDE);
    f32x4 acc[4][2];
#pragma unroll
    for (int mt = 0; mt < 4; ++mt)
#pragma unroll
      for (int nt = 0; nt < 2; ++nt)
        acc[mt][nt] = (f32x4){0.f, 0.f, 0.f, 0.f};

#pragma unroll
    for (int kk = 0; kk < 8; ++kk) {
#pragma unroll
      for (int nt = 0; nt < 2; ++nt) {
        const int row = nt * 16 + l15;
        const char* bp = zb + row * ROWSTRIDE + kk * 128 + l4 * 32;
        const f4 v0 = *(const f4*)bp;
        const f4 v1 = *(const f4*)(bp + 16);
        u4 pk;
        pk.x = hi2(v0.x, v0.y); pk.y = hi2(v0.z, v0.w);
        pk.z = hi2(v1.x, v1.y); pk.w = hi2(v1.z, v1.w);
        const bf16x8 b = __builtin_bit_cast(bf16x8, pk);
#pragma unroll
        for (int mt = 0; mt < 4; ++mt)
          acc[mt][nt] = __builtin_amdgcn_mfma_f32_16x16x32_bf16(a[mt][kk], b, acc[mt][nt], 0, 0, 0);
      }
    }

    // ---- store: Hb[node][h..h+3] u2-packed (R14-verified mapping) ----
    const int tb = t * 32;
#pragma unroll
    for (int nt = 0; nt < 2; ++nt) {
      const int node = tb + nt * 16 + l15;
      if (node < N) {
        ushort* rowp = Hb + (size_t)node * 256;
#pragma unroll
        for (int mt = 0; mt < 4; ++mt) {
          const int h = h0 + mt * 16 + l4 * 4;
          u2 o;
          o.x = pack2(acc[mt][nt][0], acc[mt][nt][1]);
          o.y = pack2(acc[mt][nt][2], acc[mt][nt][3]);
          *(u2*)(rowp + h) = o;
        }
      }
    }
    __syncthreads();   // drain staging vmcnt + protect buffer reuse
    cur ^= 1;
  }
#undef STAGE
}

// R7 gather engine + fused layer-2 epilogue. out[e] = sigmoid(W2.relu(sum+b1)+b2)
__global__ __launch_bounds__(128, 8) void gather_out(
    const ushort* __restrict__ Hb,
    const int* __restrict__ tnodes,
    const int* __restrict__ ptr,
    const float* __restrict__ b1,
    const float* __restrict__ W2,
    const float* __restrict__ b2,
    float* __restrict__ out,
    int E)
{
  const int lane = threadIdx.x & 63;
  const int wid  = threadIdx.x >> 6;             // 0..1
  const int e0   = blockIdx.x * 16 + wid * 8;    // this wave's 8 segments
  if (e0 >= E) return;
  const int nseg = min(8, E - e0);

  int bnd = 0;
  if (lane <= 8) bnd = ptr[min(e0 + lane, E)];   // bounds for segs e0..e0+8
  const int plo = __builtin_amdgcn_readfirstlane(__shfl(bnd, 0));
  const int phi = __builtin_amdgcn_readfirstlane(__shfl(bnd, nseg));
  const int total = phi - plo;                   // SGPR

  // per-lane epilogue coefficients: this lane owns cols lane*4 .. lane*4+3
  const int c0 = lane * 4;
  const float b1v0 = b1[c0], b1v1 = b1[c0 + 1], b1v2 = b1[c0 + 2], b1v3 = b1[c0 + 3];
  const float w2v0 = W2[c0], w2v1 = W2[c0 + 1], w2v2 = W2[c0 + 2], w2v3 = W2[c0 + 3];
  const float b2v = b2[0];

  const char* xbB = (const char*)Hb;
  const int lb = lane * 8;                       // byte offset within 512B row

  float a0 = 0.f, a1 = 0.f, a2 = 0.f, a3 = 0.f;
  int s = 0;
  int hi_s = __builtin_amdgcn_readfirstlane(__shfl(bnd, 1));

#define FLUSHOUT()                                                            \
  {                                                                           \
    float p = w2v0 * fmaxf(a0 + b1v0, 0.f);                                   \
    p = fmaf(w2v1, fmaxf(a1 + b1v1, 0.f), p);                                 \
    p = fmaf(w2v2, fmaxf(a2 + b1v2, 0.f), p);                                 \
    p = fmaf(w2v3, fmaxf(a3 + b1v3, 0.f), p);                                 \
    p += __shfl_xor(p, 1);  p += __shfl_xor(p, 2);                            \
    p += __shfl_xor(p, 4);  p += __shfl_xor(p, 8);                            \
    p += __shfl_xor(p, 16); p += __shfl_xor(p, 32);                           \
    if (lane == 0) out[e0 + s] = 1.f / (1.f + expf(-(p + b2v)));              \
    a0 = a1 = a2 = a3 = 0.f;                                                  \
  }
#define FLUSHCHK(PCUR)                                                        \
  while ((PCUR) >= hi_s) {            /* wave-uniform segment flush */        \
    FLUSHOUT()                                                                \
    ++s; hi_s = __builtin_amdgcn_readfirstlane(__shfl(bnd, min(s + 1, 8)));   \
  }
#define ACCV(V)                                                               \
  a0 += __uint_as_float((V).x << 16);                                         \
  a1 += __uint_as_float((V).x & 0xffff0000u);                                 \
  a2 += __uint_as_float((V).y << 16);                                         \
  a3 += __uint_as_float((V).y & 0xffff0000u);

  if (total > 0) {
    const int tmax = total - 1;
    u2 va[8], vb[8];
    // prologue: fill both banks; indices wave-uniform -> tnodes via s_load
#pragma unroll
    for (int k = 0; k < 8; ++k) {
      const int p = plo + min(k, tmax);
      va[k] = *(const u2*)(xbB + (size_t)tnodes[p] * 512 + lb);
    }
#pragma unroll
    for (int k = 0; k < 8; ++k) {
      const int p = plo + min(8 + k, tmax);
      vb[k] = *(const u2*)(xbB + (size_t)tnodes[p] * 512 + lb);
    }

    for (int j = 0; j < total; j += 16) {
      // consume bank A (pairs j..j+8)
#pragma unroll
      for (int k = 0; k < 8; ++k) {
        const int pc = j + k;
        if (pc < total) { FLUSHCHK(plo + pc) ACCV(va[k]) }
      }
      // refill bank A for pairs [j+16, j+24)
#pragma unroll
      for (int k = 0; k < 8; ++k) {
        const int p = plo + min(j + 16 + k, tmax);
        va[k] = *(const u2*)(xbB + (size_t)tnodes[p] * 512 + lb);
      }
      // consume bank B (pairs j+8..j+16)
#pragma unroll
      for (int k = 0; k < 8; ++k) {
        const int pc = j + 8 + k;
        if (pc < total) { FLUSHCHK(plo + pc) ACCV(vb[k]) }
      }
      // refill bank B for pairs [j+24, j+32)
#pragma unroll
      for (int k = 0; k < 8; ++k) {
        const int p = plo + min(j + 24 + k, tmax);
        vb[k] = *(const u2*)(xbB + (size_t)tnodes[p] * 512 + lb);
      }
    }
  }
  // flush remaining segments (incl. trailing empties)
  while (s < nseg) { FLUSHOUT() ++s; }
#undef FLUSHCHK
#undef FLUSHOUT
#undef ACCV
}

// ---------------- R4 fused fallback (ws too small for split path) ----------
__global__ __launch_bounds__(256, 4) void henn_main(
    const float* __restrict__ x,
    const int* __restrict__ tnodes,
    const int* __restrict__ ptr,
    const ushort* __restrict__ W1b,
    const float* __restrict__ b1,
    const float* __restrict__ W2,
    const float* __restrict__ b2,
    float* __restrict__ out,
    int E)
{
  __shared__ __align__(16) ushort Zb[64 * 256];
  const int tid  = threadIdx.x;
  const int wid  = tid >> 6;
  const int lane = tid & 63;
  const int l15  = lane & 15;
  const int l4   = lane >> 4;
  const int e0   = blockIdx.x * 64;

  int bidx = e0 + wid * 16 + lane;
  int bnd = 0;
  if (lane < 17) bnd = ptr[min(bidx, E)];

  for (int s = 0; s < 16; ++s) {
    const int lo = __shfl(bnd, s);
    const int hi = __shfl(bnd, s + 1);
    float4 a0 = {0,0,0,0}, a1 = {0,0,0,0}, a2 = {0,0,0,0}, a3 = {0,0,0,0};
    for (int base = lo; base < hi; base += 64) {
      const int cnt = min(64, hi - base);
      const int nd = (lane < cnt) ? tnodes[base + lane] : 0;
      const int rounds = (cnt + 3) >> 2;
      for (int r = 0; r < rounds; ++r) {
        const int idx = r * 4 + l4;
        const int node = __shfl(nd, min(idx, cnt - 1));
        if (idx < cnt) {
          const float4* rowp = (const float4*)(x + (size_t)node * 256) + l15;
          const float4 v0 = rowp[0];
          const float4 v1 = rowp[16];
          const float4 v2 = rowp[32];
          const float4 v3 = rowp[48];
          a0.x += v0.x; a0.y += v0.y; a0.z += v0.z; a0.w += v0.w;
          a1.x += v1.x; a1.y += v1.y; a1.z += v1.z; a1.w += v1.w;
          a2.x += v2.x; a2.y += v2.y; a2.z += v2.z; a2.w += v2.w;
          a3.x += v3.x; a3.y += v3.y; a3.z += v3.z; a3.w += v3.w;
        }
      }
    }
    a0.x += __shfl_xor(a0.x,16); a0.y += __shfl_xor(a0.y,16); a0.z += __shfl_xor(a0.z,16); a0.w += __shfl_xor(a0.w,16);
    a0.x += __shfl_xor(a0.x,32); a0.y += __shfl_xor(a0.y,32); a0.z += __shfl_xor(a0.z,32); a0.w += __shfl_xor(a0.w,32);
    a1.x += __shfl_xor(a1.x,16); a1.y += __shfl_xor(a1.y,16); a1.z += __shfl_xor(a1.z,16); a1.w += __shfl_xor(a1.w,16);
    a1.x += __shfl_xor(a1.x,32); a1.y += __shfl_xor(a1.y,32); a1.z += __shfl_xor(a1.z,32); a1.w += __shfl_xor(a1.w,32);
    a2.x += __shfl_xor(a2.x,16); a2.y += __shfl_xor(a2.y,16); a2.z += __shfl_xor(a2.z,16); a2.w += __shfl_xor(a2.w,16);
    a2.x += __shfl_xor(a2.x,32); a2.y += __shfl_xor(a2.y,32); a2.z += __shfl_xor(a2.z,32); a2.w += __shfl_xor(a2.w,32);
    a3.x += __shfl_xor(a3.x,16); a3.y += __shfl_xor(a3.y,16); a3.z += __shfl_xor(a3.z,16); a3.w += __shfl_xor(a3.w,16);
    a3.x += __shfl_xor(a3.x,32); a3.y += __shfl_xor(a3.y,32); a3.z += __shfl_xor(a3.z,32); a3.w += __shfl_xor(a3.w,32);
    float4 m = (l4 == 0) ? a0 : (l4 == 1) ? a1 : (l4 == 2) ? a2 : a3;
    const int row = wid * 16 + s;
    ushort4 o; o.x = f2bf(m.x); o.y = f2bf(m.y); o.z = f2bf(m.z); o.w = f2bf(m.w);
    const int waddr = row * 512 + lane * 8;
    *(ushort4*)((char*)Zb + (waddr ^ ((row & 7) << 4))) = o;
  }
  __syncthreads();

  const int n0 = wid * 64;
  f32x4 acc[4][4];
#pragma unroll
  for (int mt = 0; mt < 4; ++mt)
#pragma unroll
    for (int nt = 0; nt < 4; ++nt)
      acc[mt][nt] = (f32x4){0.f, 0.f, 0.f, 0.f};
#pragma unroll
  for (int kk = 0; kk < 8; ++kk) {
    bf16x8 a[4];
#pragma unroll
    for (int mt = 0; mt < 4; ++mt) {
      const int row = mt * 16 + l15;
      const int raddr = row * 512 + kk * 64 + l4 * 16;
      a[mt] = *(const bf16x8*)((const char*)Zb + (raddr ^ ((row & 7) << 4)));
    }
#pragma unroll
    for (int nt = 0; nt < 4; ++nt) {
      const int h = n0 + nt * 16 + l15;
      const bf16x8 b = *(const bf16x8*)(W1b + (size_t)h * 256 + kk * 32 + l4 * 8);
#pragma unroll
      for (int mt = 0; mt < 4; ++mt)
        acc[mt][nt] = __builtin_amdgcn_mfma_f32_16x16x32_bf16(a[mt], b, acc[mt][nt], 0, 0, 0);
    }
  }
  __syncthreads();

  float b1h[4], w2v[4];
#pragma unroll
  for (int nt = 0; nt < 4; ++nt) {
    const int h = n0 + nt * 16 + l15;
    b1h[nt] = b1[h];
    w2v[nt] = W2[h];
  }
  float* red = (float*)Zb;
#pragma unroll
  for (int mt = 0; mt < 4; ++mt) {
#pragma unroll
    for (int r = 0; r < 4; ++r) {
      float p = 0.f;
#pragma unroll
      for (int nt = 0; nt < 4; ++nt) {
        const float y = acc[mt][nt][r] + b1h[nt];
        p = fmaf(w2v[nt], fmaxf(y, 0.f), p);
      }
      p += __shfl_xor(p, 1);
      p += __shfl_xor(p, 2);
      p += __shfl_xor(p, 4);
      p += __shfl_xor(p, 8);
      if (l15 == 0) red[wid * 64 + mt * 16 + l4 * 4 + r] = p;
    }
  }
  __syncthreads();

  if (tid < 64) {
    const int e = e0 + tid;
    if (e < E) {
      const float v = red[tid] + red[64 + tid] + red[128 + tid] + red[192 + tid] + b2[0];
      out[e] = 1.f / (1.f + expf(-v));
    }
  }
}

extern "C" void kernel_launch(void* const* d_in, const int* in_sizes, int n_in,
                              void* d_out, int out_size, void* d_ws, size_t ws_size,
                              hipStream_t stream) {
  const float* x      = (const float*)d_in[0];
  const int*   tnodes = (const int*)d_in[1];
  const int*   tids   = (const int*)d_in[2];
  const float* W1     = (const float*)d_in[3];
  const float* b1     = (const float*)d_in[4];
  const float* W2     = (const float*)d_in[5];
  const float* b2     = (const float*)d_in[6];
  (void)n_in;

  const int P       = in_sizes[1];        // 800000
  const int E       = out_size;           // 100000
  const int n_nodes = in_sizes[0] / 256;  // 100000

  const size_t OFF_W1B  = 512 * 1024;
  const size_t OFF_HB   = 1024 * 1024;
  const size_t hb_bytes = (size_t)n_nodes * 512 + 65536;
  const size_t need     = OFF_HB + hb_bytes;

  int*    seg_ptr = (int*)d_ws;
  ushort* W1b     = (ushort*)((char*)d_ws + OFF_W1B);
  ushort* Hb      = (ushort*)((char*)d_ws + OFF_HB);

  const int prep_grid = PREP_W1_BLOCKS + (P + 255) / 256;
  prep2<<<prep_grid, 256, 0, stream>>>(W1, W1b, tids, seg_ptr, P, E);

  if (ws_size >= need) {
    const int T = (n_nodes + 31) / 32;
    const int gemm_blocks = (T < GEMM_BLOCKS) ? T : GEMM_BLOCKS;
    gemm_h<<<gemm_blocks, 256, 0, stream>>>(x, W1b, Hb, n_nodes, T);
    const int gblocks = (E + 15) / 16;
    gather_out<<<gblocks, 128, 0, stream>>>(Hb, tnodes, seg_ptr, b1, W2, b2,
                                            (float*)d_out, E);
  } else {
    const int blocks = (E + 63) / 64;
    henn_main<<<blocks, 256, 0, stream>>>(x, tnodes, seg_ptr, W1b, b1, W2, b2,
                                          (float*)d_out, E);
  }
}